// Round 4
// baseline (102.721 us; speedup 1.0000x reference)
//
#include <hip/hip_runtime.h>
#include <hip/hip_fp16.h>

// SoftNCutsLoss via rank-2 separable factorization of the bilateral weight.
// w = exp(-(Iw-I0)^2/100)*wz(dz) ; exp(Iw*I0/50) ~= 1 + Iw*I0/50 (rel err <= 2e-4)
//  => w ~= g(I0)*g(Iw)*wz + [g(I0)*I0/50]*[g(Iw)*Iw]*wz,  g(u)=exp(-u^2/100)
// Pipeline (3 launches):
//   passx   : per b, ALL 5 fields (4 preds + den): u_m, 9-wide box along x,
//             half2 pack; also writes A[b][v] = half2(g, g*I/50)
//   passyz  : 9-wide box along y + 3-tap z-comb via lane shuffles (z == lanes)
//   contract: rank-2 recombine + EPS-pad den fix + fused einsums + block
//             reduce + replicated atomics + LAST-BLOCK final (ticket)

constexpr int Pdim = 64;
constexpr int P3   = Pdim * Pdim * Pdim;   // 262144
constexpr int NREP = 16;

#define EPSF 2.2204460492503131e-16f

constexpr float WZ1   = 0.8290291181804004f;     // exp(-3/16)
constexpr float K2F   = 0.014426950408889634f;   // log2(e)/100
constexpr float C1F   = 0.02f;                   // 1/50
constexpr float WFULL = 81.0f * (1.0f + 2.0f * WZ1);

// ---------------------------------------------------------------------------
// Pass X (merged over 5 fields of one b). 128 thr: z=lane, 2 y-lines/block.
// Grid: (ygroup 32, b 4, xseg 4). Each xseg: ingest 24 x, emit 16.
// ---------------------------------------------------------------------------
__global__ __launch_bounds__(128)
void ncuts_passx(const float* __restrict__ batch, const float* __restrict__ preds,
                 __half2* __restrict__ U, __half2* __restrict__ A,
                 float* __restrict__ acc, unsigned* __restrict__ ticket) {
  const int t = threadIdx.x;
  if (blockIdx.x == 0 && blockIdx.y == 0 && blockIdx.z == 0) {
    acc[t * 4 + 0] = 0.f; acc[t * 4 + 1] = 0.f;       // 512 accumulators
    acc[t * 4 + 2] = 0.f; acc[t * 4 + 3] = 0.f;
    if (t == 0) *ticket = 0u;
  }
  const int z = t & 63, yh = t >> 6;
  const int y = blockIdx.x * 2 + yh;
  const int b = blockIdx.y;
  const int X0 = 16 * (int)blockIdx.z - 4;
  const int lin = (y << 6) + z;
  const float* Ip = batch + b * P3 + lin;
  const float* Pp = preds + b * 4 * P3 + lin;
  __half2* Ub = U + (b * 5) * P3 + lin;
  __half2* Ab = A + b * P3 + lin;

  float w[10][9], sum[10];
#pragma unroll
  for (int f = 0; f < 10; ++f) {
    sum[f] = 0.f;
#pragma unroll
    for (int i = 0; i < 9; ++i) w[f][i] = 0.f;
  }

#pragma unroll
  for (int i = 0; i < 24; ++i) {
    const int x = X0 + i;
    float u[10];
    if ((unsigned)x < 64u) {                 // scalar branch (x uniform)
      float I = Ip[x << 12];
      float g = exp2f(-I * I * K2F);
#pragma unroll
      for (int c = 0; c < 4; ++c) {
        float p = Pp[c * P3 + (x << 12)];
        u[2 * c]     = g * p;
        u[2 * c + 1] = u[2 * c] * I;
      }
      u[8] = g; u[9] = g * I;
      if (i >= 4 && i < 20)                  // x in this segment's output range
        Ab[x << 12] = __floats2half2_rn(g, g * I * C1F);
    } else {
#pragma unroll
      for (int f = 0; f < 10; ++f) u[f] = 0.f;
    }
    const int r = i % 9;                     // static after unroll
#pragma unroll
    for (int f = 0; f < 10; ++f) { sum[f] += u[f] - w[f][r]; w[f][r] = u[f]; }
    if (i >= 8) {
      const int xo = x - 4;
#pragma unroll
      for (int c = 0; c < 5; ++c)
        Ub[c * P3 + (xo << 12)] = __floats2half2_rn(sum[2 * c], sum[2 * c + 1]);
    }
  }
}

// ---------------------------------------------------------------------------
// Pass YZ: 9-wide y box (registers) + 3-tap z-comb via shuffles (z = lane).
// Grid: (xgroup 16, pair 20, yseg 4). 256 thr: z=lane, 4 x/block.
// ---------------------------------------------------------------------------
__global__ __launch_bounds__(256)
void ncuts_passyz(const __half2* __restrict__ U, __half2* __restrict__ V) {
  const int t = threadIdx.x;
  const int z = t & 63, xh = t >> 6;
  const int x = blockIdx.x * 4 + xh;
  const int pair = blockIdx.y;
  const int Y0 = 16 * (int)blockIdx.z - 4;
  const __half2* src = U + pair * P3 + (x << 12) + z;
  __half2* dst = V + pair * P3 + (x << 12) + z;

  float w0[9], w1[9];
#pragma unroll
  for (int i = 0; i < 9; ++i) { w0[i] = 0.f; w1[i] = 0.f; }
  float s0 = 0.f, s1 = 0.f;
#pragma unroll
  for (int i = 0; i < 24; ++i) {
    const int y = Y0 + i;
    float u0 = 0.f, u1 = 0.f;
    if ((unsigned)y < 64u) {
      float2 u = __half22float2(src[y << 6]);
      u0 = u.x; u1 = u.y;
    }
    const int r = i % 9;
    s0 += u0 - w0[r]; w0[r] = u0;
    s1 += u1 - w1[r]; w1[r] = u1;
    if (i >= 8) {
      float up0 = __shfl_up(s0, 1, 64),   up1 = __shfl_up(s1, 1, 64);
      float dn0 = __shfl_down(s0, 1, 64), dn1 = __shfl_down(s1, 1, 64);
      if (z == 0)  { up0 = 0.f; up1 = 0.f; }   // volume edge == wave edge
      if (z == 63) { dn0 = 0.f; dn1 = 0.f; }
      float v0 = __builtin_fmaf(WZ1, up0 + dn0, s0);
      float v1 = __builtin_fmaf(WZ1, up1 + dn1, s1);
      dst[(y - 4) << 6] = __floats2half2_rn(v0, v1);
    }
  }
}

// ---------------------------------------------------------------------------
// Contract: 2 voxels/thread (z-pair), rank-2 recombine, den boundary fix,
// fused einsums, block reduce, replicated atomics, last-block final.
// ---------------------------------------------------------------------------
__global__ __launch_bounds__(256)
void ncuts_contract(const float* __restrict__ preds, const __half2* __restrict__ A,
                    const __half2* __restrict__ V, float* __restrict__ acc,
                    unsigned* __restrict__ ticket, float* __restrict__ out) {
  __shared__ float red[4][32];
  __shared__ int islast;
  const int t   = threadIdx.x;
  const int idx = blockIdx.x * 256 + t;
  const int v0  = idx << 1;                        // even voxel; +1 is its pair
  const int z = v0 & 63, y = (v0 >> 6) & 63, x = v0 >> 12;

  float a0[4][2], a1[4][2], gsum[2] = {0.f, 0.f};
#pragma unroll
  for (int b = 0; b < 4; ++b) {
    float2 raw = *(const float2*)(A + b * P3 + v0);
    float2 f0 = __half22float2(__builtin_bit_cast(__half2, raw.x));
    float2 f1 = __half22float2(__builtin_bit_cast(__half2, raw.y));
    a0[b][0] = f0.x; a1[b][0] = f0.y;
    a0[b][1] = f1.x; a1[b][1] = f1.y;
    gsum[0] += f0.x; gsum[1] += f1.x;
  }

  float ns[4][2] = {{0.f,0.f},{0.f,0.f},{0.f,0.f},{0.f,0.f}};
  float ds[2] = {0.f, 0.f};
#pragma unroll
  for (int b = 0; b < 4; ++b) {
#pragma unroll
    for (int c = 0; c < 5; ++c) {
      float2 raw = *(const float2*)(V + (b * 5 + c) * P3 + v0);
      float2 u0 = __half22float2(__builtin_bit_cast(__half2, raw.x));
      float2 u1 = __half22float2(__builtin_bit_cast(__half2, raw.y));
      float zc0 = __builtin_fmaf(a0[b][0], u0.x, a1[b][0] * u0.y);
      float zc1 = __builtin_fmaf(a0[b][1], u1.x, a1[b][1] * u1.y);
      if (c < 4) { ns[c][0] += zc0; ns[c][1] += zc1; }
      else       { ds[0]    += zc0; ds[1]    += zc1; }
    }
  }
  // den boundary correction: out-of-bounds image cells get w ~= g(I0)*wz(dz)
  float cx = 9.f - (float)max(0, 4 - x) - (float)max(0, x - 59);
  float cy = 9.f - (float)max(0, 4 - y) - (float)max(0, y - 59);
  float cz0 = 1.f + WZ1 * ((z > 0 ? 1.f : 0.f) + 1.f);          // z even <= 62
  float cz1 = 1.f + WZ1 * (1.f + (z + 1 < 63 ? 1.f : 0.f));
  ds[0] = __builtin_fmaf(gsum[0], WFULL - cx * cy * cz0, ds[0]);
  ds[1] = __builtin_fmaf(gsum[1], WFULL - cx * cy * cz1, ds[1]);

  float pn[16], pd[16];
#pragma unroll
  for (int b = 0; b < 4; ++b) {
#pragma unroll
    for (int k = 0; k < 4; ++k) {
      float2 p = *(const float2*)(preds + (b * 4 + k) * P3 + v0);
      pn[b * 4 + k] = p.x * ns[k][0] + p.y * ns[k][1];
      pd[b * 4 + k] = p.x * ds[0]    + p.y * ds[1];
    }
  }

#pragma unroll
  for (int i = 0; i < 16; ++i) {
#pragma unroll
    for (int off = 32; off > 0; off >>= 1) {
      pn[i] += __shfl_down(pn[i], off, 64);
      pd[i] += __shfl_down(pd[i], off, 64);
    }
  }
  const int wave = t >> 6, lane = t & 63;
  if (lane == 0) {
#pragma unroll
    for (int i = 0; i < 16; ++i) { red[wave][i] = pn[i]; red[wave][16 + i] = pd[i]; }
  }
  __syncthreads();
  if (t < 32) {
    float s = red[0][t] + red[1][t] + red[2][t] + red[3][t];
    atomicAdd(&acc[(blockIdx.x & (NREP - 1)) * 32 + t], s);
  }
  // ---- last-block final ----
  __syncthreads();              // drains vmcnt: this block's atomics complete
  if (t == 0) {
    unsigned done = atomicAdd(ticket, 1u);        // device-scope RMW
    islast = (done == gridDim.x - 1);
  }
  __syncthreads();
  if (islast) {
    if (t < 32) {
      float n = 0.f;
      for (int r = 0; r < NREP; ++r) n += atomicAdd(&acc[r * 32 + t], 0.f);  // coherent read
      red[0][t] = n;
    }
    __syncthreads();
    if (t < 4) {
      float s = 0.f;
      for (int k = 0; k < 4; ++k)
        s += (red[0][t * 4 + k] + EPSF) / (red[0][16 + t * 4 + k] + EPSF);
      out[t] = 4.0f - s;
    }
  }
}

// ===========================================================================
// Fallback (round-1 direct kernel) if the workspace is too small.
// ===========================================================================
constexpr int Rxy = 4;
constexpr int TXf = 8, TYf = 8;
constexpr int ZLEN = 2;
constexpr int RGX = 16, RGY = 16, RGZ = 10;
constexpr int YPf = 17, ZPf = 11;

__global__ __launch_bounds__(256, 2)
void ncuts_mainf(const float* __restrict__ batch, const float* __restrict__ preds,
                 float* __restrict__ acc) {
  __shared__ float  sB[RGX][YPf][ZPf];
  __shared__ float4 sP[RGX][YPf][ZPf];
  __shared__ float  red[4][32];

  const int t = threadIdx.x;
  const int tx = t & 7, ty = (t >> 3) & 7, tzt = t >> 6;
  const int bx0 = blockIdx.x * TXf, by0 = blockIdx.y * TYf, bz0 = blockIdx.z * 8;
  const int x = bx0 + tx, y = by0 + ty, z0 = bz0 + tzt * ZLEN;
  const int zc = tzt * ZLEN;

  float  den[ZLEN];
  float4 num[ZLEN];
#pragma unroll
  for (int j = 0; j < ZLEN; ++j) { den[j] = 0.f; num[j] = make_float4(0.f, 0.f, 0.f, 0.f); }

  const float C1 = -0.014426950408889634f;
  const float LWZ1 = -0.27050531991668065f;

  for (int b = 0; b < 4; ++b) {
    __syncthreads();
    for (int idx = t; idx < RGX * RGY * RGZ; idx += 256) {
      int rz = idx % RGZ, rq = idx / RGZ, ry = rq % RGY, rx = rq / RGY;
      int gx = bx0 + rx - Rxy, gy = by0 + ry - Rxy, gz = bz0 + rz - 1;
      bool in = ((unsigned)gx < 64u) & ((unsigned)gy < 64u) & ((unsigned)gz < 64u);
      float v = EPSF; float4 pv = make_float4(EPSF, EPSF, EPSF, EPSF);
      if (in) {
        int gi = (gx * Pdim + gy) * Pdim + gz;
        v = batch[b * P3 + gi];
        const float* pp = preds + b * 4 * P3 + gi;
        pv.x = pp[0]; pv.y = pp[P3]; pv.z = pp[2 * P3]; pv.w = pp[3 * P3];
      }
      sB[rx][ry][rz] = v; sP[rx][ry][rz] = pv;
    }
    __syncthreads();

    float I0[ZLEN];
#pragma unroll
    for (int j = 0; j < ZLEN; ++j) I0[j] = sB[tx + Rxy][ty + Rxy][zc + 1 + j];

#pragma unroll 1
    for (int dy = 0; dy < 9; ++dy) {
#pragma unroll 3
      for (int dx = 0; dx < 9; ++dx) {
        const float*  cb = &sB[tx + dx][ty + dy][zc];
        const float4* cp = &sP[tx + dx][ty + dy][zc];
        float colB[ZLEN + 2]; float4 colP[ZLEN + 2];
#pragma unroll
        for (int j = 0; j < ZLEN + 2; ++j) { colB[j] = cb[j]; colP[j] = cp[j]; }
#pragma unroll
        for (int j = 0; j < ZLEN; ++j) {
#pragma unroll
          for (int dz = 0; dz < 3; ++dz) {
            float d = colB[j + dz] - I0[j];
            float arg = __builtin_fmaf(d * d, C1, (dz == 1) ? 0.f : LWZ1);
            float w = exp2f(arg);
            den[j] += w;
            float4 p = colP[j + dz];
            num[j].x = __builtin_fmaf(w, p.x, num[j].x);
            num[j].y = __builtin_fmaf(w, p.y, num[j].y);
            num[j].z = __builtin_fmaf(w, p.z, num[j].z);
            num[j].w = __builtin_fmaf(w, p.w, num[j].w);
          }
        }
      }
    }
  }

  float pn[16], pd[16];
#pragma unroll
  for (int i = 0; i < 16; ++i) { pn[i] = 0.f; pd[i] = 0.f; }
#pragma unroll
  for (int b = 0; b < 4; ++b) {
#pragma unroll
    for (int j = 0; j < ZLEN; ++j) {
      const float* pp = preds + b * 4 * P3 + ((x * Pdim + y) * Pdim + z0 + j);
      float nsv[4] = {num[j].x, num[j].y, num[j].z, num[j].w};
#pragma unroll
      for (int k = 0; k < 4; ++k) {
        float pv = pp[k * P3];
        pn[b * 4 + k] = __builtin_fmaf(pv, nsv[k], pn[b * 4 + k]);
        pd[b * 4 + k] = __builtin_fmaf(pv, den[j], pd[b * 4 + k]);
      }
    }
  }
#pragma unroll
  for (int i = 0; i < 16; ++i) {
#pragma unroll
    for (int off = 32; off > 0; off >>= 1) {
      pn[i] += __shfl_down(pn[i], off, 64);
      pd[i] += __shfl_down(pd[i], off, 64);
    }
  }
  const int wave = t >> 6, lane = t & 63;
  if (lane == 0) {
#pragma unroll
    for (int i = 0; i < 16; ++i) { red[wave][i] = pn[i]; red[wave][16 + i] = pd[i]; }
  }
  __syncthreads();
  if (t < 32) {
    float s = red[0][t] + red[1][t] + red[2][t] + red[3][t];
    int bid = blockIdx.x + 8 * (blockIdx.y + 8 * (int)blockIdx.z);
    atomicAdd(&acc[(bid & (NREP - 1)) * 32 + t], s);
  }
}

__global__ void ncuts_zero(float* __restrict__ acc) {
  int t = threadIdx.x;
  if (t < NREP * 32) acc[t] = 0.f;
}

__global__ void ncuts_final(const float* __restrict__ acc, float* __restrict__ out) {
  __shared__ float loss[16];
  int t = threadIdx.x;
  if (t < 16) {
    float n = 0.f, d = 0.f;
    for (int r = 0; r < NREP; ++r) { n += acc[r * 32 + t]; d += acc[r * 32 + 16 + t]; }
    loss[t] = (n + EPSF) / (d + EPSF);
  }
  __syncthreads();
  if (t < 4) {
    float s = loss[t * 4] + loss[t * 4 + 1] + loss[t * 4 + 2] + loss[t * 4 + 3];
    out[t] = 4.0f - s;
  }
}

// ===========================================================================
extern "C" void kernel_launch(void* const* d_in, const int* in_sizes, int n_in,
                              void* d_out, int out_size, void* d_ws, size_t ws_size,
                              hipStream_t stream) {
  const float* batch = (const float*)d_in[0];
  const float* preds = (const float*)d_in[1];
  float* out = (float*)d_out;

  const size_t ub = (size_t)20 * P3 * sizeof(__half2);   // U: 20 MB
  const size_t vb = ub;                                   // V: 20 MB
  const size_t ab = (size_t)4 * P3 * sizeof(__half2);     // A: 4 MB
  const size_t need = ub + vb + ab + 8192;
  if (ws_size >= need) {
    char* base = (char*)d_ws;
    __half2*  U      = (__half2*)(base + 256);
    __half2*  V      = (__half2*)(base + 256 + ub);
    __half2*  A      = (__half2*)(base + 256 + ub + vb);
    float*    acc    = (float*)(base + 512 + ub + vb + ab);      // 512 floats
    unsigned* ticket = (unsigned*)(base + 512 + ub + vb + ab + 2048);
    hipLaunchKernelGGL(ncuts_passx, dim3(32, 4, 4), dim3(128), 0, stream,
                       batch, preds, U, A, acc, ticket);
    hipLaunchKernelGGL(ncuts_passyz, dim3(16, 20, 4), dim3(256), 0, stream, U, V);
    hipLaunchKernelGGL(ncuts_contract, dim3(512), dim3(256), 0, stream,
                       preds, A, V, acc, ticket, out);
  } else {
    float* acc = (float*)d_ws;
    hipLaunchKernelGGL(ncuts_zero, dim3(1), dim3(512), 0, stream, acc);
    hipLaunchKernelGGL(ncuts_mainf, dim3(8, 8, 8), dim3(256), 0, stream,
                       batch, preds, acc);
    hipLaunchKernelGGL(ncuts_final, dim3(1), dim3(64), 0, stream, acc, out);
  }
}

// Round 5
// 102.183 us; speedup vs baseline: 1.0053x; 1.0053x over previous
//
#include <hip/hip_runtime.h>
#include <hip/hip_fp16.h>

// SoftNCutsLoss via rank-2 separable factorization of the bilateral weight.
// w = exp(-(Iw-I0)^2/100)*wz(dz) ; exp(Iw*I0/50) ~= 1 + Iw*I0/50 (rel err <= 2e-4)
//  => w ~= g(I0)*g(Iw)*wz + [g(I0)*I0/50]*[g(Iw)*Iw]*wz,  g(u)=exp(-u^2/100)
// Pipeline (3 launches):
//   passx   : per (b,c) field pair: u_m = g*I^m*p, 9-wide box along x, half2
//             pack. 4 x-segments for TLP (1280 blocks, 20 waves/CU).
//   passyz  : 9-wide box along y + 3-tap z-comb via lane shuffles (z == lanes),
//             4 y-segments.
//   contract: 2 voxels/thread, recompute g from batch, rank-2 recombine +
//             EPS-pad den fix + fused einsums + block reduce + replicated
//             atomics + LAST-BLOCK final (ticket).

constexpr int Pdim = 64;
constexpr int P3   = Pdim * Pdim * Pdim;   // 262144
constexpr int NREP = 16;

#define EPSF 2.2204460492503131e-16f

constexpr float WZ1   = 0.8290291181804004f;     // exp(-3/16)
constexpr float K2F   = 0.014426950408889634f;   // log2(e)/100
constexpr float C1F   = 0.02f;                   // 1/50
constexpr float WFULL = 81.0f * (1.0f + 2.0f * WZ1);

// ---------------------------------------------------------------------------
// Pass X: half2(U0,U1) = BoxX(g*p, g*I*p). thread = (y,z); scans 24 x, emits 16.
// Grid: (ygroup 16, pair 20, xseg 4), 256 thr (4 y-lines x 64 z-lanes).
// ---------------------------------------------------------------------------
__global__ __launch_bounds__(256)
void ncuts_passx(const float* __restrict__ batch, const float* __restrict__ preds,
                 __half2* __restrict__ U, float* __restrict__ acc,
                 unsigned* __restrict__ ticket) {
  const int t = threadIdx.x;
  if (blockIdx.x == 0 && blockIdx.y == 0 && blockIdx.z == 0) {
    acc[t] = 0.f; acc[t + 256] = 0.f;       // zero NREP*32 = 512 accumulators
    if (t == 0) *ticket = 0u;
  }
  const int z = t & 63, yh = t >> 6;
  const int y = blockIdx.x * 4 + yh;
  const int pair = blockIdx.y;              // b*5 + c; c=0..3 pred, c=4 den
  const int b = pair / 5, c = pair - 5 * b;
  const bool isden = (c == 4);
  const int X0 = 16 * (int)blockIdx.z - 4;
  const int lin = (y << 6) + z;
  const float* Ip = batch + b * P3 + lin;
  const float* Pp = isden ? Ip : preds + (b * 4 + c) * P3 + lin;
  __half2* Uo = U + pair * P3 + lin;

  float w0[9], w1[9];
#pragma unroll
  for (int i = 0; i < 9; ++i) { w0[i] = 0.f; w1[i] = 0.f; }
  float s0 = 0.f, s1 = 0.f;
#pragma unroll
  for (int i = 0; i < 24; ++i) {
    const int x = X0 + i;
    float u0 = 0.f, u1 = 0.f;
    if ((unsigned)x < 64u) {                // x uniform across block: scalar branch
      float I = Ip[x << 12];
      float g = exp2f(-I * I * K2F);
      float p = isden ? 1.f : Pp[x << 12];
      u0 = g * p;
      u1 = u0 * I;
    }
    const int r = i % 9;                    // static after full unroll
    s0 += u0 - w0[r]; w0[r] = u0;
    s1 += u1 - w1[r]; w1[r] = u1;
    if (i >= 8) Uo[(x - 4) << 12] = __floats2half2_rn(s0, s1);
  }
}

// ---------------------------------------------------------------------------
// Pass YZ: 9-wide y box (registers) + 3-tap z-comb via shuffles (z = lane).
// Grid: (xgroup 16, pair 20, yseg 4), 256 thr (4 x x 64 z). Scan 24 y, emit 16.
// ---------------------------------------------------------------------------
__global__ __launch_bounds__(256)
void ncuts_passyz(const __half2* __restrict__ U, __half2* __restrict__ V) {
  const int t = threadIdx.x;
  const int z = t & 63, xh = t >> 6;
  const int x = blockIdx.x * 4 + xh;
  const int pair = blockIdx.y;
  const int Y0 = 16 * (int)blockIdx.z - 4;
  const __half2* src = U + pair * P3 + (x << 12) + z;
  __half2* dst = V + pair * P3 + (x << 12) + z;

  float w0[9], w1[9];
#pragma unroll
  for (int i = 0; i < 9; ++i) { w0[i] = 0.f; w1[i] = 0.f; }
  float s0 = 0.f, s1 = 0.f;
#pragma unroll
  for (int i = 0; i < 24; ++i) {
    const int y = Y0 + i;
    float u0 = 0.f, u1 = 0.f;
    if ((unsigned)y < 64u) {
      float2 u = __half22float2(src[y << 6]);
      u0 = u.x; u1 = u.y;
    }
    const int r = i % 9;
    s0 += u0 - w0[r]; w0[r] = u0;
    s1 += u1 - w1[r]; w1[r] = u1;
    if (i >= 8) {
      float up0 = __shfl_up(s0, 1, 64),   up1 = __shfl_up(s1, 1, 64);
      float dn0 = __shfl_down(s0, 1, 64), dn1 = __shfl_down(s1, 1, 64);
      if (z == 0)  { up0 = 0.f; up1 = 0.f; }   // volume edge == wave edge
      if (z == 63) { dn0 = 0.f; dn1 = 0.f; }
      float v0 = __builtin_fmaf(WZ1, up0 + dn0, s0);
      float v1 = __builtin_fmaf(WZ1, up1 + dn1, s1);
      dst[(y - 4) << 6] = __floats2half2_rn(v0, v1);
    }
  }
}

// ---------------------------------------------------------------------------
// Contract: 2 voxels/thread (z-pair), recompute g, rank-2 recombine, den
// boundary fix, fused einsums, block reduce, replicated atomics, last-block
// final via ticket.
// ---------------------------------------------------------------------------
__global__ __launch_bounds__(256)
void ncuts_contract(const float* __restrict__ batch, const float* __restrict__ preds,
                    const __half2* __restrict__ V, float* __restrict__ acc,
                    unsigned* __restrict__ ticket, float* __restrict__ out) {
  __shared__ float red[4][32];
  __shared__ int islast;
  const int t   = threadIdx.x;
  const int idx = blockIdx.x * 256 + t;
  const int v0  = idx << 1;                 // even voxel; +1 is its pair
  const int z = v0 & 63, y = (v0 >> 6) & 63, x = v0 >> 12;

  float a0[4][2], a1[4][2], gsum[2] = {0.f, 0.f};
#pragma unroll
  for (int b = 0; b < 4; ++b) {
    float2 I = *(const float2*)(batch + b * P3 + v0);
    float g0 = exp2f(-I.x * I.x * K2F);
    float g1 = exp2f(-I.y * I.y * K2F);
    a0[b][0] = g0; a1[b][0] = g0 * I.x * C1F;
    a0[b][1] = g1; a1[b][1] = g1 * I.y * C1F;
    gsum[0] += g0; gsum[1] += g1;
  }

  float ns[4][2] = {{0.f,0.f},{0.f,0.f},{0.f,0.f},{0.f,0.f}};
  float ds[2] = {0.f, 0.f};
#pragma unroll
  for (int b = 0; b < 4; ++b) {
#pragma unroll
    for (int c = 0; c < 5; ++c) {
      float2 raw = *(const float2*)(V + (b * 5 + c) * P3 + v0);
      float2 u0 = __half22float2(__builtin_bit_cast(__half2, raw.x));
      float2 u1 = __half22float2(__builtin_bit_cast(__half2, raw.y));
      float zc0 = __builtin_fmaf(a0[b][0], u0.x, a1[b][0] * u0.y);
      float zc1 = __builtin_fmaf(a0[b][1], u1.x, a1[b][1] * u1.y);
      if (c < 4) { ns[c][0] += zc0; ns[c][1] += zc1; }
      else       { ds[0]    += zc0; ds[1]    += zc1; }
    }
  }
  // den boundary correction: out-of-bounds image cells get w ~= g(I0)*wz(dz)
  float cx = 9.f - (float)max(0, 4 - x) - (float)max(0, x - 59);
  float cy = 9.f - (float)max(0, 4 - y) - (float)max(0, y - 59);
  float cz0 = 1.f + WZ1 * ((z > 0 ? 1.f : 0.f) + 1.f);      // z even <= 62
  float cz1 = 1.f + WZ1 * (1.f + (z + 1 < 63 ? 1.f : 0.f));
  ds[0] = __builtin_fmaf(gsum[0], WFULL - cx * cy * cz0, ds[0]);
  ds[1] = __builtin_fmaf(gsum[1], WFULL - cx * cy * cz1, ds[1]);

  float pn[16], pd[16];
#pragma unroll
  for (int b = 0; b < 4; ++b) {
#pragma unroll
    for (int k = 0; k < 4; ++k) {
      float2 p = *(const float2*)(preds + (b * 4 + k) * P3 + v0);
      pn[b * 4 + k] = p.x * ns[k][0] + p.y * ns[k][1];
      pd[b * 4 + k] = p.x * ds[0]    + p.y * ds[1];
    }
  }

#pragma unroll
  for (int i = 0; i < 16; ++i) {
#pragma unroll
    for (int off = 32; off > 0; off >>= 1) {
      pn[i] += __shfl_down(pn[i], off, 64);
      pd[i] += __shfl_down(pd[i], off, 64);
    }
  }
  const int wave = t >> 6, lane = t & 63;
  if (lane == 0) {
#pragma unroll
    for (int i = 0; i < 16; ++i) { red[wave][i] = pn[i]; red[wave][16 + i] = pd[i]; }
  }
  __syncthreads();
  if (t < 32) {
    float s = red[0][t] + red[1][t] + red[2][t] + red[3][t];
    atomicAdd(&acc[(blockIdx.x & (NREP - 1)) * 32 + t], s);
  }
  // ---- last-block final ----
  __syncthreads();              // drains vmcnt: this block's atomics complete
  if (t == 0) {
    unsigned done = atomicAdd(ticket, 1u);            // device-scope RMW
    islast = (done == gridDim.x - 1);
  }
  __syncthreads();
  if (islast) {
    if (t < 32) {
      float n = 0.f;
      for (int r = 0; r < NREP; ++r) n += atomicAdd(&acc[r * 32 + t], 0.f);  // coherent read
      red[0][t] = n;
    }
    __syncthreads();
    if (t < 4) {
      float s = 0.f;
      for (int k = 0; k < 4; ++k)
        s += (red[0][t * 4 + k] + EPSF) / (red[0][16 + t * 4 + k] + EPSF);
      out[t] = 4.0f - s;
    }
  }
}

// ===========================================================================
// Fallback (round-1 direct kernel) if the workspace is too small.
// ===========================================================================
constexpr int Rxy = 4;
constexpr int TXf = 8, TYf = 8;
constexpr int ZLEN = 2;
constexpr int RGX = 16, RGY = 16, RGZ = 10;
constexpr int YPf = 17, ZPf = 11;

__global__ __launch_bounds__(256, 2)
void ncuts_mainf(const float* __restrict__ batch, const float* __restrict__ preds,
                 float* __restrict__ acc) {
  __shared__ float  sB[RGX][YPf][ZPf];
  __shared__ float4 sP[RGX][YPf][ZPf];
  __shared__ float  red[4][32];

  const int t = threadIdx.x;
  const int tx = t & 7, ty = (t >> 3) & 7, tzt = t >> 6;
  const int bx0 = blockIdx.x * TXf, by0 = blockIdx.y * TYf, bz0 = blockIdx.z * 8;
  const int x = bx0 + tx, y = by0 + ty, z0 = bz0 + tzt * ZLEN;
  const int zc = tzt * ZLEN;

  float  den[ZLEN];
  float4 num[ZLEN];
#pragma unroll
  for (int j = 0; j < ZLEN; ++j) { den[j] = 0.f; num[j] = make_float4(0.f, 0.f, 0.f, 0.f); }

  const float C1 = -0.014426950408889634f;
  const float LWZ1 = -0.27050531991668065f;

  for (int b = 0; b < 4; ++b) {
    __syncthreads();
    for (int idx = t; idx < RGX * RGY * RGZ; idx += 256) {
      int rz = idx % RGZ, rq = idx / RGZ, ry = rq % RGY, rx = rq / RGY;
      int gx = bx0 + rx - Rxy, gy = by0 + ry - Rxy, gz = bz0 + rz - 1;
      bool in = ((unsigned)gx < 64u) & ((unsigned)gy < 64u) & ((unsigned)gz < 64u);
      float v = EPSF; float4 pv = make_float4(EPSF, EPSF, EPSF, EPSF);
      if (in) {
        int gi = (gx * Pdim + gy) * Pdim + gz;
        v = batch[b * P3 + gi];
        const float* pp = preds + b * 4 * P3 + gi;
        pv.x = pp[0]; pv.y = pp[P3]; pv.z = pp[2 * P3]; pv.w = pp[3 * P3];
      }
      sB[rx][ry][rz] = v; sP[rx][ry][rz] = pv;
    }
    __syncthreads();

    float I0[ZLEN];
#pragma unroll
    for (int j = 0; j < ZLEN; ++j) I0[j] = sB[tx + Rxy][ty + Rxy][zc + 1 + j];

#pragma unroll 1
    for (int dy = 0; dy < 9; ++dy) {
#pragma unroll 3
      for (int dx = 0; dx < 9; ++dx) {
        const float*  cb = &sB[tx + dx][ty + dy][zc];
        const float4* cp = &sP[tx + dx][ty + dy][zc];
        float colB[ZLEN + 2]; float4 colP[ZLEN + 2];
#pragma unroll
        for (int j = 0; j < ZLEN + 2; ++j) { colB[j] = cb[j]; colP[j] = cp[j]; }
#pragma unroll
        for (int j = 0; j < ZLEN; ++j) {
#pragma unroll
          for (int dz = 0; dz < 3; ++dz) {
            float d = colB[j + dz] - I0[j];
            float arg = __builtin_fmaf(d * d, C1, (dz == 1) ? 0.f : LWZ1);
            float w = exp2f(arg);
            den[j] += w;
            float4 p = colP[j + dz];
            num[j].x = __builtin_fmaf(w, p.x, num[j].x);
            num[j].y = __builtin_fmaf(w, p.y, num[j].y);
            num[j].z = __builtin_fmaf(w, p.z, num[j].z);
            num[j].w = __builtin_fmaf(w, p.w, num[j].w);
          }
        }
      }
    }
  }

  float pn[16], pd[16];
#pragma unroll
  for (int i = 0; i < 16; ++i) { pn[i] = 0.f; pd[i] = 0.f; }
#pragma unroll
  for (int b = 0; b < 4; ++b) {
#pragma unroll
    for (int j = 0; j < ZLEN; ++j) {
      const float* pp = preds + b * 4 * P3 + ((x * Pdim + y) * Pdim + z0 + j);
      float nsv[4] = {num[j].x, num[j].y, num[j].z, num[j].w};
#pragma unroll
      for (int k = 0; k < 4; ++k) {
        float pv = pp[k * P3];
        pn[b * 4 + k] = __builtin_fmaf(pv, nsv[k], pn[b * 4 + k]);
        pd[b * 4 + k] = __builtin_fmaf(pv, den[j], pd[b * 4 + k]);
      }
    }
  }
#pragma unroll
  for (int i = 0; i < 16; ++i) {
#pragma unroll
    for (int off = 32; off > 0; off >>= 1) {
      pn[i] += __shfl_down(pn[i], off, 64);
      pd[i] += __shfl_down(pd[i], off, 64);
    }
  }
  const int wave = t >> 6, lane = t & 63;
  if (lane == 0) {
#pragma unroll
    for (int i = 0; i < 16; ++i) { red[wave][i] = pn[i]; red[wave][16 + i] = pd[i]; }
  }
  __syncthreads();
  if (t < 32) {
    float s = red[0][t] + red[1][t] + red[2][t] + red[3][t];
    int bid = blockIdx.x + 8 * (blockIdx.y + 8 * (int)blockIdx.z);
    atomicAdd(&acc[(bid & (NREP - 1)) * 32 + t], s);
  }
}

__global__ void ncuts_zero(float* __restrict__ acc) {
  int t = threadIdx.x;
  if (t < NREP * 32) acc[t] = 0.f;
}

__global__ void ncuts_final(const float* __restrict__ acc, float* __restrict__ out) {
  __shared__ float loss[16];
  int t = threadIdx.x;
  if (t < 16) {
    float n = 0.f, d = 0.f;
    for (int r = 0; r < NREP; ++r) { n += acc[r * 32 + t]; d += acc[r * 32 + 16 + t]; }
    loss[t] = (n + EPSF) / (d + EPSF);
  }
  __syncthreads();
  if (t < 4) {
    float s = loss[t * 4] + loss[t * 4 + 1] + loss[t * 4 + 2] + loss[t * 4 + 3];
    out[t] = 4.0f - s;
  }
}

// ===========================================================================
extern "C" void kernel_launch(void* const* d_in, const int* in_sizes, int n_in,
                              void* d_out, int out_size, void* d_ws, size_t ws_size,
                              hipStream_t stream) {
  const float* batch = (const float*)d_in[0];
  const float* preds = (const float*)d_in[1];
  float* out = (float*)d_out;

  const size_t ub = (size_t)20 * P3 * sizeof(__half2);   // U: 20 MB
  const size_t vb = ub;                                  // V: 20 MB
  const size_t need = ub + vb + 8192;
  if (ws_size >= need) {
    char* base = (char*)d_ws;
    __half2*  U      = (__half2*)(base + 256);
    __half2*  V      = (__half2*)(base + 256 + ub);
    float*    acc    = (float*)(base + 512 + ub + vb);   // 512 floats
    unsigned* ticket = (unsigned*)(base + 512 + ub + vb + 2048);
    hipLaunchKernelGGL(ncuts_passx, dim3(16, 20, 4), dim3(256), 0, stream,
                       batch, preds, U, acc, ticket);
    hipLaunchKernelGGL(ncuts_passyz, dim3(16, 20, 4), dim3(256), 0, stream, U, V);
    hipLaunchKernelGGL(ncuts_contract, dim3(512), dim3(256), 0, stream,
                       batch, preds, V, acc, ticket, out);
  } else {
    float* acc = (float*)d_ws;
    hipLaunchKernelGGL(ncuts_zero, dim3(1), dim3(512), 0, stream, acc);
    hipLaunchKernelGGL(ncuts_mainf, dim3(8, 8, 8), dim3(256), 0, stream,
                       batch, preds, acc);
    hipLaunchKernelGGL(ncuts_final, dim3(1), dim3(64), 0, stream, acc, out);
  }
}